// Round 1
// baseline (78.091 us; speedup 1.0000x reference)
//
#include <hip/hip_runtime.h>
#include <cstdint>

#define SBLOCK 256
#define QCHUNK 512
#define SENTINEL 0x7fffffff

// ---------------------------------------------------------------------------
// Kernel 1: initialize per-query min-index workspace to SENTINEL.
// ---------------------------------------------------------------------------
__global__ void init_idx(int* __restrict__ minidx, int batch) {
    int t = blockIdx.x * blockDim.x + threadIdx.x;
    if (t < batch) minidx[t] = SENTINEL;
}

// ---------------------------------------------------------------------------
// Kernel 2: brute-force exact-match scan.
// Each block: one 256-star chunk  x  one 512-query chunk (staged in LDS).
// TF semantics: first flat True in (N,2) equality -> row = min i where
// (obs.x == qx) || (obs.y == qy).  Hits are rare -> atomicMin is cheap.
// ---------------------------------------------------------------------------
__global__ __launch_bounds__(SBLOCK)
void scan_kernel(const float2* __restrict__ obs,
                 const float2* __restrict__ qpos,
                 int* __restrict__ minidx,
                 int n_stars, int batch) {
    __shared__ float2 q[QCHUNK];

    const int qbase = blockIdx.y * QCHUNK;

    // Cooperative load of this block's query chunk into LDS.
    for (int j = threadIdx.x; j < QCHUNK; j += SBLOCK) {
        int qi = qbase + j;
        if (qi < batch) {
            q[j] = qpos[qi];
        } else {
            float nanv = __int_as_float(0x7fc00000);
            q[j] = make_float2(nanv, nanv);   // NaN never compares equal
        }
    }
    __syncthreads();

    const int i = blockIdx.x * SBLOCK + threadIdx.x;
    float sx, sy;
    if (i < n_stars) {
        float2 s = obs[i];
        sx = s.x; sy = s.y;
    } else {
        sx = __int_as_float(0x7fc00000);      // NaN: matches nothing
        sy = sx;
    }

    #pragma unroll 8
    for (int j = 0; j < QCHUNK; ++j) {
        float2 Q = q[j];                      // same-address broadcast (free)
        if (sx == Q.x || sy == Q.y) {
            atomicMin(&minidx[qbase + j], i);
        }
    }
}

// ---------------------------------------------------------------------------
// Kernel 3: gather zks_prior rows per query.  Sentinel (no match) -> row 0,
// matching argmax-of-all-false == 0 in the reference.
// ---------------------------------------------------------------------------
__global__ void gather_kernel(const float* __restrict__ zks,
                              const int* __restrict__ minidx,
                              float* __restrict__ out,
                              int batch, int n_zk) {
    int t = blockIdx.x * blockDim.x + threadIdx.x;
    int total = batch * n_zk;
    if (t >= total) return;
    int b = t / n_zk;
    int k = t - b * n_zk;
    int idx = minidx[b];
    if (idx == SENTINEL) idx = 0;
    out[t] = zks[(long long)idx * n_zk + k];
}

// ---------------------------------------------------------------------------
extern "C" void kernel_launch(void* const* d_in, const int* in_sizes, int n_in,
                              void* d_out, int out_size, void* d_ws, size_t ws_size,
                              hipStream_t stream) {
    const float2* qpos = (const float2*)d_in[0];   // positions (B, 2)
    const float2* obs  = (const float2*)d_in[1];   // obs_pos  (N, 2)
    const float*  zks  = (const float*)d_in[2];    // zks_prior (N, nz)

    const int batch   = in_sizes[0] / 2;
    const int n_stars = in_sizes[1] / 2;
    const int n_zk    = in_sizes[2] / n_stars;

    float* out   = (float*)d_out;
    int* minidx  = (int*)d_ws;                      // batch ints of scratch

    init_idx<<<(batch + 255) / 256, 256, 0, stream>>>(minidx, batch);

    dim3 grid((n_stars + SBLOCK - 1) / SBLOCK,
              (batch + QCHUNK - 1) / QCHUNK);
    scan_kernel<<<grid, SBLOCK, 0, stream>>>(obs, qpos, minidx, n_stars, batch);

    int total = batch * n_zk;
    gather_kernel<<<(total + 255) / 256, 256, 0, stream>>>(zks, minidx, out,
                                                           batch, n_zk);
}

// Round 2
// 41.946 us; speedup vs baseline: 1.8617x; 1.8617x over previous
//
#include <hip/hip_runtime.h>
#include <cstdint>

// ---------------------------------------------------------------------------
// Exact-match index lookup via two hash tables (x-coord and y-coord).
// Reference semantics: idx = min row i where obs.x==qx OR obs.y==qy.
//   => idx = min( lookup_x(qx), lookup_y(qy) )
// Queries are exact rows of obs_pos, so lookup always succeeds.
// ---------------------------------------------------------------------------

#define LOG2_TABLE 18
#define TABLE_SIZE (1u << LOG2_TABLE)      // 262144 slots, load factor ~0.38
#define TABLE_MASK (TABLE_SIZE - 1u)
#define EMPTY_KEY  0xFFFFFFFFu             // NaN bit pattern: cannot occur in data
#define NO_IDX     0xFFFFFFFFu

__device__ __forceinline__ uint32_t hmix(uint32_t x) {
    x ^= x >> 16; x *= 0x7feb352du;
    x ^= x >> 15; x *= 0x846ca68bu;
    x ^= x >> 16;
    return x;
}

__device__ __forceinline__ void ht_insert(uint32_t* __restrict__ keys,
                                          uint32_t* __restrict__ vals,
                                          uint32_t kb, uint32_t idx) {
    uint32_t h = hmix(kb) & TABLE_MASK;
    for (;;) {
        uint32_t k = keys[h];
        if (k == kb) { atomicMin(&vals[h], idx); return; }
        if (k == EMPTY_KEY) {
            uint32_t old = atomicCAS(&keys[h], EMPTY_KEY, kb);
            if (old == EMPTY_KEY || old == kb) { atomicMin(&vals[h], idx); return; }
            // slot stolen by a different key: keep probing
        }
        h = (h + 1u) & TABLE_MASK;
    }
}

__device__ __forceinline__ uint32_t ht_lookup(const uint32_t* __restrict__ keys,
                                              const uint32_t* __restrict__ vals,
                                              uint32_t kb) {
    uint32_t h = hmix(kb) & TABLE_MASK;
    for (;;) {
        uint32_t k = keys[h];
        if (k == kb) return vals[h];
        if (k == EMPTY_KEY) return NO_IDX;
        h = (h + 1u) & TABLE_MASK;
    }
}

// ---------------------------------------------------------------------------
// Kernel 1: insert all stars into both tables.
// ---------------------------------------------------------------------------
__global__ void build_kernel(const float2* __restrict__ obs,
                             uint32_t* __restrict__ ws, int n_stars) {
    int i = blockIdx.x * blockDim.x + threadIdx.x;
    if (i >= n_stars) return;
    uint32_t* kx = ws;
    uint32_t* vx = ws + TABLE_SIZE;
    uint32_t* ky = ws + 2u * TABLE_SIZE;
    uint32_t* vy = ws + 3u * TABLE_SIZE;
    float2 s = obs[i];
    ht_insert(kx, vx, __float_as_uint(s.x), (uint32_t)i);
    ht_insert(ky, vy, __float_as_uint(s.y), (uint32_t)i);
}

// ---------------------------------------------------------------------------
// Kernel 2: one wave per query. All 64 lanes walk the same (broadcast) hash
// chain; lanes 0..n_zk-1 then write the gathered zks row.
// ---------------------------------------------------------------------------
__global__ void probe_gather_kernel(const float2* __restrict__ qpos,
                                    const float* __restrict__ zks,
                                    const uint32_t* __restrict__ ws,
                                    float* __restrict__ out,
                                    int batch, int n_zk) {
    int gid  = blockIdx.x * blockDim.x + threadIdx.x;
    int wid  = gid >> 6;
    int lane = gid & 63;
    if (wid >= batch) return;

    const uint32_t* kx = ws;
    const uint32_t* vx = ws + TABLE_SIZE;
    const uint32_t* ky = ws + 2u * TABLE_SIZE;
    const uint32_t* vy = ws + 3u * TABLE_SIZE;

    float2 q = qpos[wid];
    uint32_t ix = ht_lookup(kx, vx, __float_as_uint(q.x));
    uint32_t iy = ht_lookup(ky, vy, __float_as_uint(q.y));
    uint32_t idx = ix < iy ? ix : iy;
    if (idx == NO_IDX) idx = 0;   // all-false argmax -> 0 (can't happen here)

    if (lane < n_zk)
        out[(long long)wid * n_zk + lane] = zks[(long long)idx * n_zk + lane];
}

// ---------------------------------------------------------------------------
// Fallback brute force (only if ws_size is too small for the tables).
// ---------------------------------------------------------------------------
#define SBLOCK 256
#define QCHUNK 512
#define SENTINEL 0x7fffffff

__global__ void init_idx(int* __restrict__ minidx, int batch) {
    int t = blockIdx.x * blockDim.x + threadIdx.x;
    if (t < batch) minidx[t] = SENTINEL;
}

__global__ __launch_bounds__(SBLOCK)
void scan_kernel(const float2* __restrict__ obs,
                 const float2* __restrict__ qpos,
                 int* __restrict__ minidx,
                 int n_stars, int batch) {
    __shared__ float2 q[QCHUNK];
    const int qbase = blockIdx.y * QCHUNK;
    for (int j = threadIdx.x; j < QCHUNK; j += SBLOCK) {
        int qi = qbase + j;
        if (qi < batch) q[j] = qpos[qi];
        else { float nv = __int_as_float(0x7fc00000); q[j] = make_float2(nv, nv); }
    }
    __syncthreads();
    const int i = blockIdx.x * SBLOCK + threadIdx.x;
    float sx, sy;
    if (i < n_stars) { float2 s = obs[i]; sx = s.x; sy = s.y; }
    else { sx = __int_as_float(0x7fc00000); sy = sx; }
    #pragma unroll 8
    for (int j = 0; j < QCHUNK; ++j) {
        float2 Q = q[j];
        if (sx == Q.x || sy == Q.y) atomicMin(&minidx[qbase + j], i);
    }
}

__global__ void gather_kernel(const float* __restrict__ zks,
                              const int* __restrict__ minidx,
                              float* __restrict__ out,
                              int batch, int n_zk) {
    int t = blockIdx.x * blockDim.x + threadIdx.x;
    int total = batch * n_zk;
    if (t >= total) return;
    int b = t / n_zk;
    int k = t - b * n_zk;
    int idx = minidx[b];
    if (idx == SENTINEL) idx = 0;
    out[t] = zks[(long long)idx * n_zk + k];
}

// ---------------------------------------------------------------------------
extern "C" void kernel_launch(void* const* d_in, const int* in_sizes, int n_in,
                              void* d_out, int out_size, void* d_ws, size_t ws_size,
                              hipStream_t stream) {
    const float2* qpos = (const float2*)d_in[0];   // positions (B, 2)
    const float2* obs  = (const float2*)d_in[1];   // obs_pos  (N, 2)
    const float*  zks  = (const float*)d_in[2];    // zks_prior (N, nz)

    const int batch   = in_sizes[0] / 2;
    const int n_stars = in_sizes[1] / 2;
    const int n_zk    = in_sizes[2] / n_stars;

    float* out = (float*)d_out;

    const size_t table_bytes = (size_t)4 * TABLE_SIZE * sizeof(uint32_t); // 4 MiB

    if (ws_size >= table_bytes) {
        uint32_t* ws = (uint32_t*)d_ws;
        hipMemsetAsync(ws, 0xFF, table_bytes, stream);   // keys=EMPTY, vals=UINT_MAX
        build_kernel<<<(n_stars + 255) / 256, 256, 0, stream>>>(obs, ws, n_stars);
        int threads = batch * 64;
        probe_gather_kernel<<<(threads + 255) / 256, 256, 0, stream>>>(
            qpos, zks, ws, out, batch, n_zk);
    } else {
        int* minidx = (int*)d_ws;
        init_idx<<<(batch + 255) / 256, 256, 0, stream>>>(minidx, batch);
        dim3 grid((n_stars + SBLOCK - 1) / SBLOCK, (batch + QCHUNK - 1) / QCHUNK);
        scan_kernel<<<grid, SBLOCK, 0, stream>>>(obs, qpos, minidx, n_stars, batch);
        int total = batch * n_zk;
        gather_kernel<<<(total + 255) / 256, 256, 0, stream>>>(zks, minidx, out,
                                                               batch, n_zk);
    }
}

// Round 3
// 39.399 us; speedup vs baseline: 1.9820x; 1.0646x over previous
//
#include <hip/hip_runtime.h>
#include <cstdint>

// ---------------------------------------------------------------------------
// Exact-match index lookup via two hash tables (x-coord and y-coord).
// Reference semantics: idx = min row i where obs.x==qx OR obs.y==qy.
//   => idx = min( lookup_x(qx), lookup_y(qy) )
// Entry layout: one u64 per slot = (key_bits << 32) | min_index.
// EMPTY = 0xFFFFFFFFFFFFFFFF (key 0xFFFFFFFF is a NaN pattern; cannot occur).
// ---------------------------------------------------------------------------

#define LOG2_TABLE 18
#define TABLE_SIZE (1u << LOG2_TABLE)      // 262144 slots/table, load ~0.38
#define TABLE_MASK (TABLE_SIZE - 1u)
#define EMPTY64    0xFFFFFFFFFFFFFFFFull
#define NO_IDX     0xFFFFFFFFu

typedef unsigned long long u64;

__device__ __forceinline__ uint32_t hmix(uint32_t x) {
    x ^= x >> 16; x *= 0x7feb352du;
    x ^= x >> 15; x *= 0x846ca68bu;
    x ^= x >> 16;
    return x;
}

__device__ __forceinline__ void ht_insert(u64* __restrict__ tab,
                                          uint32_t kb, uint32_t idx) {
    u64 pack = ((u64)kb << 32) | (u64)idx;
    uint32_t h = hmix(kb) & TABLE_MASK;
    for (;;) {
        u64 cur = tab[h];
        if ((uint32_t)(cur >> 32) == kb) {
            // Key fixed forever once set; same high bits -> 64-bit min == idx min.
            atomicMin(&tab[h], pack);
            return;
        }
        if (cur == EMPTY64) {
            u64 old = atomicCAS(&tab[h], EMPTY64, pack);
            if (old == EMPTY64) return;
            if ((uint32_t)(old >> 32) == kb) { atomicMin(&tab[h], pack); return; }
            // slot stolen by different key: keep probing
        }
        h = (h + 1u) & TABLE_MASK;
    }
}

__device__ __forceinline__ uint32_t ht_lookup(const u64* __restrict__ tab,
                                              uint32_t kb) {
    uint32_t h = hmix(kb) & TABLE_MASK;
    for (;;) {
        u64 cur = tab[h];
        if ((uint32_t)(cur >> 32) == kb) return (uint32_t)cur;
        if (cur == EMPTY64) return NO_IDX;
        h = (h + 1u) & TABLE_MASK;
    }
}

// ---------------------------------------------------------------------------
// Kernel 0: clear both tables (4 MiB) with 16B stores, one iteration/thread.
// (hipMemsetAsync's fill kernel measured 41 us at 101 GB/s for this -- do it
//  ourselves with a properly sized grid.)
// ---------------------------------------------------------------------------
__global__ void clear_kernel(ulonglong2* __restrict__ ws, int n16) {
    int t = blockIdx.x * blockDim.x + threadIdx.x;
    if (t < n16) ws[t] = make_ulonglong2(EMPTY64, EMPTY64);
}

// ---------------------------------------------------------------------------
// Kernel 1: insert all stars into both tables.
// ---------------------------------------------------------------------------
__global__ void build_kernel(const float2* __restrict__ obs,
                             u64* __restrict__ ws, int n_stars) {
    int i = blockIdx.x * blockDim.x + threadIdx.x;
    if (i >= n_stars) return;
    u64* tx = ws;
    u64* ty = ws + TABLE_SIZE;
    float2 s = obs[i];
    ht_insert(tx, __float_as_uint(s.x), (uint32_t)i);
    ht_insert(ty, __float_as_uint(s.y), (uint32_t)i);
}

// ---------------------------------------------------------------------------
// Kernel 2: one wave per query. All 64 lanes walk the same (broadcast) hash
// chain; lanes 0..n_zk-1 then write the gathered zks row.
// ---------------------------------------------------------------------------
__global__ void probe_gather_kernel(const float2* __restrict__ qpos,
                                    const float* __restrict__ zks,
                                    const u64* __restrict__ ws,
                                    float* __restrict__ out,
                                    int batch, int n_zk) {
    int gid  = blockIdx.x * blockDim.x + threadIdx.x;
    int wid  = gid >> 6;
    int lane = gid & 63;
    if (wid >= batch) return;

    const u64* tx = ws;
    const u64* ty = ws + TABLE_SIZE;

    float2 q = qpos[wid];
    uint32_t ix = ht_lookup(tx, __float_as_uint(q.x));
    uint32_t iy = ht_lookup(ty, __float_as_uint(q.y));
    uint32_t idx = ix < iy ? ix : iy;
    if (idx == NO_IDX) idx = 0;   // all-false argmax -> 0 (can't happen here)

    if (lane < n_zk)
        out[(long long)wid * n_zk + lane] = zks[(long long)idx * n_zk + lane];
}

// ---------------------------------------------------------------------------
// Fallback brute force (only if ws_size is too small for the tables).
// ---------------------------------------------------------------------------
#define SBLOCK 256
#define QCHUNK 512
#define SENTINEL 0x7fffffff

__global__ void init_idx(int* __restrict__ minidx, int batch) {
    int t = blockIdx.x * blockDim.x + threadIdx.x;
    if (t < batch) minidx[t] = SENTINEL;
}

__global__ __launch_bounds__(SBLOCK)
void scan_kernel(const float2* __restrict__ obs,
                 const float2* __restrict__ qpos,
                 int* __restrict__ minidx,
                 int n_stars, int batch) {
    __shared__ float2 q[QCHUNK];
    const int qbase = blockIdx.y * QCHUNK;
    for (int j = threadIdx.x; j < QCHUNK; j += SBLOCK) {
        int qi = qbase + j;
        if (qi < batch) q[j] = qpos[qi];
        else { float nv = __int_as_float(0x7fc00000); q[j] = make_float2(nv, nv); }
    }
    __syncthreads();
    const int i = blockIdx.x * SBLOCK + threadIdx.x;
    float sx, sy;
    if (i < n_stars) { float2 s = obs[i]; sx = s.x; sy = s.y; }
    else { sx = __int_as_float(0x7fc00000); sy = sx; }
    #pragma unroll 8
    for (int j = 0; j < QCHUNK; ++j) {
        float2 Q = q[j];
        if (sx == Q.x || sy == Q.y) atomicMin(&minidx[qbase + j], i);
    }
}

__global__ void gather_kernel(const float* __restrict__ zks,
                              const int* __restrict__ minidx,
                              float* __restrict__ out,
                              int batch, int n_zk) {
    int t = blockIdx.x * blockDim.x + threadIdx.x;
    int total = batch * n_zk;
    if (t >= total) return;
    int b = t / n_zk;
    int k = t - b * n_zk;
    int idx = minidx[b];
    if (idx == SENTINEL) idx = 0;
    out[t] = zks[(long long)idx * n_zk + k];
}

// ---------------------------------------------------------------------------
extern "C" void kernel_launch(void* const* d_in, const int* in_sizes, int n_in,
                              void* d_out, int out_size, void* d_ws, size_t ws_size,
                              hipStream_t stream) {
    const float2* qpos = (const float2*)d_in[0];   // positions (B, 2)
    const float2* obs  = (const float2*)d_in[1];   // obs_pos  (N, 2)
    const float*  zks  = (const float*)d_in[2];    // zks_prior (N, nz)

    const int batch   = in_sizes[0] / 2;
    const int n_stars = in_sizes[1] / 2;
    const int n_zk    = in_sizes[2] / n_stars;

    float* out = (float*)d_out;

    const size_t table_bytes = (size_t)2 * TABLE_SIZE * sizeof(u64); // 4 MiB

    if (ws_size >= table_bytes) {
        u64* ws = (u64*)d_ws;
        int n16 = (int)(table_bytes / 16);           // 262144 x 16B stores
        clear_kernel<<<(n16 + 255) / 256, 256, 0, stream>>>((ulonglong2*)ws, n16);
        build_kernel<<<(n_stars + 255) / 256, 256, 0, stream>>>(obs, ws, n_stars);
        int threads = batch * 64;
        probe_gather_kernel<<<(threads + 255) / 256, 256, 0, stream>>>(
            qpos, zks, ws, out, batch, n_zk);
    } else {
        int* minidx = (int*)d_ws;
        init_idx<<<(batch + 255) / 256, 256, 0, stream>>>(minidx, batch);
        dim3 grid((n_stars + SBLOCK - 1) / SBLOCK, (batch + QCHUNK - 1) / QCHUNK);
        scan_kernel<<<grid, SBLOCK, 0, stream>>>(obs, qpos, minidx, n_stars, batch);
        int total = batch * n_zk;
        gather_kernel<<<(total + 255) / 256, 256, 0, stream>>>(zks, minidx, out,
                                                               batch, n_zk);
    }
}